// Round 4
// baseline (504.791 us; speedup 1.0000x reference)
//
#include <hip/hip_runtime.h>
#include <math.h>

#define NCH 192
#define NB 8
#define SPAT 32768           // 32^3
#define TILE_M 64
#define TPW 8                                 // tiles per workgroup
#define NWG_P 512                             // pipelined-pass grid (64 WG per sample)
#define NELEM_PER_B ((size_t)NCH * SPAT)      // 6291456

typedef short s16x8 __attribute__((ext_vector_type(8)));
typedef float f32x4 __attribute__((ext_vector_type(4)));

__device__ __forceinline__ float bf2f(unsigned short h) {
  return __uint_as_float(((unsigned)h) << 16);
}
__device__ __forceinline__ unsigned short f2bf(float f) {
  unsigned u = __float_as_uint(f);
  u += 0x7FFF + ((u >> 16) & 1);   // round-to-nearest-even
  return (unsigned short)(u >> 16);
}

// erf via Abramowitz-Stegun 7.1.26, |abs err| < 1.5e-7
__device__ __forceinline__ float erf_fast(float x) {
  float ax = fabsf(x);
  float t = 1.0f / fmaf(0.3275911f, ax, 1.0f);
  float p = t * fmaf(t, fmaf(t, fmaf(t, fmaf(t, 1.061405429f, -1.453152027f),
                                     1.421413741f), -0.284496736f), 0.254829592f);
  float r = 1.0f - p * __expf(-ax * ax);
  return copysignf(r, x);
}
__device__ __forceinline__ float gelu_exact(float x) {
  return 0.5f * x * (1.0f + erf_fast(x * 0.70710678118654752f));
}

// reflect-shift source position: out[i] = x[i-s], reflect(-1)->1, reflect(32)->30
template <int AX>  // 0 none, 2=D, 3=H, 4=W
__device__ __forceinline__ int shift_src(int p, int s) {
  if (AX == 0) return p;
  const int SH = (AX == 4) ? 0 : (AX == 3) ? 5 : 10;
  int i = (p >> SH) & 31;
  int j = i - s;
  j = (j < 0) ? 1 : j;
  j = (j > 31) ? 30 : j;
  return p + ((j - i) << SH);
}

// LDS tile: [chunk c:3][pos p:64][ch-in-chunk u:64] bf16 (128B rows).
// Granule (16B) swizzle: g7 = (u>>3) ^ (p&7) ^ (p>>3)  — spreads both the
// compute-phase column reads (2-way) and K1's per-position b16 writes (2-way).
// SINGLE helper used by every LDS access (both-sides rule #21).
__device__ __forceinline__ int lds_off(int c, int p, int u) {
  return (c * 64 + p) * 128 + 16 * (((u >> 3) ^ (p & 7) ^ (p >> 3)) & 7) + 2 * (u & 7);
}

// ---------------------------------------------------------------------------
// Pipelined GEMM pass: each WG owns TPW consecutive 64-pos tiles of one sample.
// Weights live in registers for the whole WG; LDS double-buffers the tile.
// Per tile: stage-write(regs->W) | issue loads(t+1) | barrier | MFMA | barrier
//           | epilogue | barrier | coop-store.  Loads overlap compute+store.
//   AX/EPI/OUTF/INF/PERB/FUSE as before.
// ---------------------------------------------------------------------------
template <int AX, int EPI, int OUTF, int INF, int PERB, int FUSE>
__global__ __launch_bounds__(256, 2)
void gemm_pass(const void* __restrict__ inv,
               const unsigned short* __restrict__ wmat,
               const float* __restrict__ bias,
               void* __restrict__ outv,
               float* __restrict__ partials,
               const float* __restrict__ AC) {
  __shared__ __align__(16) char lds[2][3 * 64 * 128];   // 2 x 24 KB
  __shared__ float acs[2 * NCH];
  __shared__ float red[4][2];

  int wg = blockIdx.x;            // 0..511
  int b = wg >> 6;
  int ti0 = (wg & 63) * TPW;      // first tile index within sample
  int tid = threadIdx.x;
  int wave = tid >> 6;
  int lane = tid & 63;
  int col = lane & 15;
  int kg = lane >> 4;

  const unsigned short* wbase = wmat + (PERB ? (size_t)b * NCH * NCH : 0);
  const float* bbase = bias + (PERB ? b * NCH : 0);
  const char* inbytes = (const char*)inv;
  const float* xin = (const float*)inv;
  float* outf = (float*)outv;

  // ---- Preload ALL weight fragments into registers (once per WG) ----
  s16x8 af[6][3];
#pragma unroll
  for (int ks = 0; ks < 6; ++ks)
#pragma unroll
    for (int r = 0; r < 3; ++r)
      af[ks][r] = *(const s16x8*)(wbase + (wave * 48 + r * 16 + col) * NCH + ks * 32 + kg * 8);

  if (FUSE)
    for (int i = tid; i < 2 * NCH; i += 256) acs[i] = AC[b * 2 * NCH + i];

  // ---- staging registers + prologue loads for tile 0 ----
  s16x8 vr[6];     // INF==0 path (24 VGPR)
  f32x4 xr[12];    // INF==1 path (48 VGPR)
  {
    int p0 = ti0 * 64;
    if (INF == 1) {
#pragma unroll
      for (int j = 0; j < 12; ++j) {
        int q = j * 256 + tid, ch = q >> 4, g = q & 15;
        xr[j] = *(const f32x4*)(xin + (size_t)b * NELEM_PER_B + (size_t)ch * SPAT + p0 + 4 * g);
      }
    } else {
#pragma unroll
      for (int j = 0; j < 6; ++j) {
        unsigned g = j * 256 + tid;
        int p = (int)(g / 24u), r24 = (int)(g - 24u * (unsigned)p);
        int ps = shift_src<AX>(p0 + p, (r24 >> 3) - 1);
        vr[j] = *(const s16x8*)(inbytes + ((size_t)b * SPAT + ps) * 384 + r24 * 16);
      }
    }
  }
  __syncthreads();   // acs visible before first FUSE use

  float ssum = 0.f, ssq = 0.f;

  for (int t = 0; t < TPW; ++t) {
    char* W = lds[t & 1];
    int p0 = (ti0 + t) * 64;

    // ---- stage-write regs -> W ----
    if (INF == 1) {
#pragma unroll
      for (int j = 0; j < 12; ++j) {
        int q = j * 256 + tid, ch = q >> 4, g = q & 15;
        int c = ch >> 6, u = ch & 63;
#pragma unroll
        for (int i = 0; i < 4; ++i)
          *(unsigned short*)(W + lds_off(c, 4 * g + i, u)) = f2bf(xr[j][i]);
      }
    } else {
#pragma unroll
      for (int j = 0; j < 6; ++j) {
        unsigned g = j * 256 + tid;
        int p = (int)(g / 24u), r24 = (int)(g - 24u * (unsigned)p);
        s16x8 v = vr[j];
        if (FUSE) {
          int ch0 = r24 * 8;
#pragma unroll
          for (int u = 0; u < 8; ++u) {
            float f = bf2f((unsigned short)v[u]);
            f = fmaf(f, acs[ch0 + u], acs[NCH + ch0 + u]);
            f = gelu_exact(f);
            v[u] = (short)f2bf(f);
          }
        }
        *(s16x8*)(W + lds_off(r24 >> 3, p, (r24 & 7) * 8)) = v;
      }
    }

    // ---- issue next tile's loads (overlap compute + store below) ----
    if (t + 1 < TPW) {
      int p1 = (ti0 + t + 1) * 64;
      if (INF == 1) {
#pragma unroll
        for (int j = 0; j < 12; ++j) {
          int q = j * 256 + tid, ch = q >> 4, g = q & 15;
          xr[j] = *(const f32x4*)(xin + (size_t)b * NELEM_PER_B + (size_t)ch * SPAT + p1 + 4 * g);
        }
      } else {
#pragma unroll
        for (int j = 0; j < 6; ++j) {
          unsigned g = j * 256 + tid;
          int p = (int)(g / 24u), r24 = (int)(g - 24u * (unsigned)p);
          int ps = shift_src<AX>(p1 + p, (r24 >> 3) - 1);
          vr[j] = *(const s16x8*)(inbytes + ((size_t)b * SPAT + ps) * 384 + r24 * 16);
        }
      }
    }
    __syncthreads();

    // ---- compute: pure ds_read + MFMA (weights already in regs) ----
    f32x4 acc[3][4] = {};
#pragma unroll
    for (int ks = 0; ks < 6; ++ks) {
      int k0 = ks * 32 + kg * 8;
      int c = k0 >> 6, u = k0 & 63;
      s16x8 bf[4];
#pragma unroll
      for (int m = 0; m < 4; ++m)
        bf[m] = *(const s16x8*)(W + lds_off(c, m * 16 + col, u));
#pragma unroll
      for (int r = 0; r < 3; ++r)
#pragma unroll
        for (int m = 0; m < 4; ++m)
          acc[r][m] = __builtin_amdgcn_mfma_f32_16x16x32_bf16(af[ks][r], bf[m], acc[r][m], 0, 0, 0);
    }
    __syncthreads();   // all B-frag reads of W done; W reusable

    // ---- epilogue: D mapping col=lane&15, row=(lane>>4)*4+j ----
#pragma unroll
    for (int r = 0; r < 3; ++r) {
      int rowb = wave * 48 + r * 16 + kg * 4;
      f32x4 bs = *(const f32x4*)(bbase + rowb);
#pragma unroll
      for (int m = 0; m < 4; ++m) {
        int p = m * 16 + col;
        float v[4];
#pragma unroll
        for (int j = 0; j < 4; ++j) {
          float tv = acc[r][m][j] + bs[j];
          if (EPI == 2) tv = gelu_exact(tv);
          if (EPI >= 1) { ssum += tv; ssq = fmaf(tv, tv, ssq); }
          v[j] = tv;
        }
        if (OUTF == 0) {
          uint2 pk;
          pk.x = (unsigned)f2bf(v[0]) | ((unsigned)f2bf(v[1]) << 16);
          pk.y = (unsigned)f2bf(v[2]) | ((unsigned)f2bf(v[3]) << 16);
          *(uint2*)(W + lds_off(rowb >> 6, p, rowb & 63)) = pk;
        } else {
#pragma unroll
          for (int j = 0; j < 4; ++j)
            outf[((size_t)b * NCH + rowb + j) * SPAT + p0 + p] = v[j];
        }
      }
    }

    if (OUTF == 0) {
      __syncthreads();
      char* outbytes = (char*)outv + ((size_t)b * SPAT + p0) * 384;
#pragma unroll
      for (int j = 0; j < 6; ++j) {
        unsigned g = j * 256 + tid;
        int p = (int)(g / 24u), r24 = (int)(g - 24u * (unsigned)p);
        s16x8 v = *(const s16x8*)(W + lds_off(r24 >> 3, p, (r24 & 7) * 8));
        *(s16x8*)(outbytes + g * 16) = v;
      }
    }
  }

  if (EPI >= 1) {
#pragma unroll
    for (int off = 1; off < 64; off <<= 1) {
      ssum += __shfl_xor(ssum, off, 64);
      ssq += __shfl_xor(ssq, off, 64);
    }
    if (lane == 0) { red[wave][0] = ssum; red[wave][1] = ssq; }
    __syncthreads();
    if (tid == 0) {
      partials[wg * 2]     = red[0][0] + red[1][0] + red[2][0] + red[3][0];
      partials[wg * 2 + 1] = red[0][1] + red[1][1] + red[2][1] + red[3][1];
    }
  }
}

// Deterministic per-sample stats finalize (64 WG partials per sample)
__global__ void stats_finalize(const float* __restrict__ partials,
                               const float* __restrict__ nw,
                               const float* __restrict__ nb,
                               float* __restrict__ AC) {
  int b = blockIdx.x;
  int tid = threadIdx.x;
  __shared__ float s0[256], s1[256];
  float a = 0.f, c = 0.f;
  for (int i = tid; i < 64; i += 256) {
    a += partials[(b * 64 + i) * 2];
    c += partials[(b * 64 + i) * 2 + 1];
  }
  s0[tid] = a; s1[tid] = c;
  __syncthreads();
  for (int st = 128; st > 0; st >>= 1) {
    if (tid < st) { s0[tid] += s0[tid + st]; s1[tid] += s1[tid + st]; }
    __syncthreads();
  }
  float inv_n = 1.0f / (float)(NELEM_PER_B);
  float mu = s0[0] * inv_n;
  float var = s1[0] * inv_n - mu * mu;
  float rs = rsqrtf(var + 1e-5f);
  if (tid < NCH) {
    float A = rs * nw[tid];
    AC[b * 2 * NCH + tid] = A;
    AC[b * 2 * NCH + NCH + tid] = nb[tid] - mu * A;
  }
}

// fp32 -> bf16 weight conversion: slots 0=w1, 1=w22, 2=w21, 3=w23
__global__ void prep_weights(const float* __restrict__ w1, const float* __restrict__ w21,
                             const float* __restrict__ w22, const float* __restrict__ w23,
                             unsigned short* __restrict__ wb) {
  int i = blockIdx.x * 256 + threadIdx.x;
  if (i >= 4 * NCH * NCH) return;
  int m = i / (NCH * NCH), r = i % (NCH * NCH);
  const float* src = (m == 0) ? w1 : (m == 1) ? w22 : (m == 2) ? w21 : w23;
  wb[i] = f2bf(src[r]);
}

// Fold norm2 affine into w3/b3 per sample
__global__ void prep_w3(const float* __restrict__ w3, const float* __restrict__ b3,
                        const float* __restrict__ AC2,
                        unsigned short* __restrict__ w3e, float* __restrict__ b3e) {
  int b = blockIdx.x;
  int o = threadIdx.x;
  if (o >= NCH) return;
  const float* A = AC2 + b * 2 * NCH;
  const float* C = A + NCH;
  float s = b3[o];
  for (int c = 0; c < NCH; ++c) {
    float w = w3[o * NCH + c];
    w3e[((size_t)b * NCH + o) * NCH + c] = f2bf(w * A[c]);
    s = fmaf(w, C[c], s);
  }
  b3e[b * NCH + o] = s;
}

extern "C" void kernel_launch(void* const* d_in, const int* in_sizes, int n_in,
                              void* d_out, int out_size, void* d_ws, size_t ws_size,
                              hipStream_t stream) {
  const float* x   = (const float*)d_in[0];
  const float* w1  = (const float*)d_in[1];
  const float* b1  = (const float*)d_in[2];
  const float* n1w = (const float*)d_in[3];
  const float* n1b = (const float*)d_in[4];
  const float* w21 = (const float*)d_in[5];
  const float* b21 = (const float*)d_in[6];
  const float* w22 = (const float*)d_in[7];
  const float* b22 = (const float*)d_in[8];
  const float* w23 = (const float*)d_in[9];
  const float* b23 = (const float*)d_in[10];
  const float* n2w = (const float*)d_in[11];
  const float* n2b = (const float*)d_in[12];
  const float* w3  = (const float*)d_in[13];
  const float* b3  = (const float*)d_in[14];

  char* ws = (char*)d_ws;
  size_t off = 0;
  unsigned short* wb = (unsigned short*)(ws + off); off += (size_t)4 * NCH * NCH * 2;
  off = (off + 255) & ~(size_t)255;
  unsigned short* w3e = (unsigned short*)(ws + off); off += (size_t)NB * NCH * NCH * 2;
  off = (off + 255) & ~(size_t)255;
  float* b3e = (float*)(ws + off); off += NB * NCH * 4;
  float* AC1 = (float*)(ws + off); off += NB * 2 * NCH * 4;
  float* AC2 = (float*)(ws + off); off += NB * 2 * NCH * 4;
  float* part1 = (float*)(ws + off); off += NWG_P * 2 * 4;
  float* part2 = (float*)(ws + off); off += NWG_P * 2 * 4;
  off = (off + 255) & ~(size_t)255;
  unsigned short* R1 = (unsigned short*)(ws + off);            // 100.7 MB in ws
  unsigned short* R2 = (unsigned short*)d_out;                 // bf16 scratch in d_out space

  prep_weights<<<(4 * NCH * NCH + 255) / 256, 256, 0, stream>>>(w1, w21, w22, w23, wb);

  // K1: x (f32 cmajor) -> R2 via pipelined LDS transpose, W=w1, stats1
  gemm_pass<0, 1, 0, 1, 0, 0><<<NWG_P, 256, 0, stream>>>(x, wb + 0 * NCH * NCH, b1, R2, part1, nullptr);
  stats_finalize<<<NB, 256, 0, stream>>>(part1, n1w, n1b, AC1);
  // K2a: fused norm1+gelu during staging, shift H(3), W=w22: R2 -> R1
  gemm_pass<3, 0, 0, 0, 0, 1><<<NWG_P, 256, 0, stream>>>(R2, wb + 1 * NCH * NCH, b22, R1, nullptr, AC1);
  // K2b: shift D(2), W=w21: R1 -> R2
  gemm_pass<2, 0, 0, 0, 0, 0><<<NWG_P, 256, 0, stream>>>(R1, wb + 2 * NCH * NCH, b21, R2, nullptr, nullptr);
  // K2c: shift W(4), W=w23, epi gelu+stats2: R2 -> R1
  gemm_pass<4, 2, 0, 0, 0, 0><<<NWG_P, 256, 0, stream>>>(R2, wb + 3 * NCH * NCH, b23, R1, part2, nullptr);
  stats_finalize<<<NB, 256, 0, stream>>>(part2, n2w, n2b, AC2);
  prep_w3<<<NB, NCH, 0, stream>>>(w3, b3, AC2, w3e, b3e);
  // K3: folded norm2 + conv3, f32 channel-major out: R1 -> d_out
  gemm_pass<0, 0, 1, 0, 1, 0><<<NWG_P, 256, 0, stream>>>(R1, w3e, b3e, d_out, part2, nullptr);
}